// Round 12
// baseline (210.783 us; speedup 1.0000x reference)
//
#include <hip/hip_runtime.h>

typedef __bf16 bf16_t;
typedef __bf16 bf16x8 __attribute__((ext_vector_type(8)));
typedef __bf16 bf16x4 __attribute__((ext_vector_type(4)));
typedef float f32x4 __attribute__((ext_vector_type(4)));

#define DEV static __device__ __forceinline__

DEV void gload16(const void* g, void* lds) {
  __builtin_amdgcn_global_load_lds((__attribute__((address_space(1))) void*)g,
                                   (__attribute__((address_space(3))) void*)lds, 16, 0, 0);
}

DEV f32x4 mfma16(bf16x8 a, bf16x8 b, f32x4 c) {
  return __builtin_amdgcn_mfma_f32_16x16x32_bf16(a, b, c, 0, 0, 0);
}

// ---------------- fused pre-pass: cvt + rope table + 3 weight transposes ----------------
DEV void transpose_blk(const float* __restrict__ in, bf16_t* __restrict__ out,
                       int R, int C, int bx, int by, int tid, float (*tile)[33]) {
  const int tx = tid & 31, ty = tid >> 5;
  const int rb = by * 32, cb = bx * 32;
#pragma unroll
  for (int i = 0; i < 32; i += 8)
    tile[ty + i][tx] = in[(size_t)(rb + ty + i) * C + (cb + tx)];
  __syncthreads();
#pragma unroll
  for (int i = 0; i < 32; i += 8)
    out[(size_t)(cb + ty + i) * R + (rb + tx)] = (bf16_t)tile[tx][ty + i];
}

__global__ __launch_bounds__(256) void k_prep(const float* __restrict__ hs,
                                              bf16_t* __restrict__ Xbf,
                                              const float* __restrict__ Wq,
                                              const float* __restrict__ Wkv,
                                              const float* __restrict__ Wo,
                                              bf16_t* __restrict__ Wqkvt,
                                              bf16_t* __restrict__ Wot,
                                              const int* __restrict__ pos_ids,
                                              float2* __restrict__ tbl) {
  __shared__ float tile[32][33];
  const int bid = blockIdx.x, tid = threadIdx.x;
  if (bid < 8192) {                              // cvt f32->bf16, 4/thread
    const int i = (bid * 256 + tid) * 4;
    float4 v = *(const float4*)(hs + i);
    bf16x4 o;
    o[0] = (bf16_t)v.x; o[1] = (bf16_t)v.y; o[2] = (bf16_t)v.z; o[3] = (bf16_t)v.w;
    *(bf16x4*)(Xbf + i) = o;
  } else if (bid < 8192 + 512) {                 // rope cos/sin table
    const int token = (bid - 8192) * 8 + (tid >> 5);
    const int d2 = tid & 31;
    const float p = (float)pos_ids[token];
    const float freq = exp2f(-(float)d2 / 32.0f * log2f(10000.0f));
    const float a = p * freq;
    tbl[token * 32 + d2] = make_float2(cosf(a), sinf(a));
  } else if (bid < 8192 + 512 + 4096) {          // Wq^T
    const int local = bid - (8192 + 512);
    transpose_blk(Wq, Wqkvt, 2048, 2048, local & 63, local >> 6, tid, tile);
  } else if (bid < 8192 + 512 + 4096 + 2048) {   // Wkv^T
    const int local = bid - (8192 + 512 + 4096);
    transpose_blk(Wkv, Wqkvt + (size_t)2048 * 2048, 2048, 1024,
                  local & 31, local >> 5, tid, tile);
  } else {                                       // Wo^T
    const int local = bid - (8192 + 512 + 4096 + 2048);
    transpose_blk(Wo, Wot, 2048, 2048, local & 63, local >> 6, tid, tile);
  }
}

// =================================================================
// Shared phase helpers
// =================================================================
#define PH_MID()                                            \
  __builtin_amdgcn_s_barrier();                             \
  asm volatile("s_waitcnt lgkmcnt(0)" ::: "memory");        \
  __builtin_amdgcn_sched_barrier(0);                        \
  __builtin_amdgcn_s_setprio(1)

#define PH_END()                                            \
  __builtin_amdgcn_s_setprio(0);                            \
  __builtin_amdgcn_s_barrier()

// =================================================================
// QKV GEMM: 256x192 tile -> grid 16x16 = 256 blocks = FULL machine
// (was 256x256 -> 192 blocks = 75% coverage, the measured limiter).
// Mirrors the proven out-proj 2-phase schedule: B frags held in regs
// across both phases; stage A1(t+1)@p0, A0/B(t+2)@p1, gate vmcnt(5)
// (retires tile t+1 completely, leaves t+2's 5 loads in flight).
// RoPE epilogue: 48-col wave spans break (d,d+32) in-register pairing,
// so acc goes through an LDS exchange (2 rounds x 128 rows x 192 cols,
// stride 193 f32) and 384 threads re-read whole 64-wide head chunks
// (192 = 3 heads; bcol multiples of 192 keep heads unsplit).
// =================================================================
#define QSTAGE_A(bi, st, h)                                                     \
  do {                                                                          \
    const bf16_t* _s = gA + (size_t)(brow + (h) * 128 + r0) * 2048 + (st) * 64 + l0 * 8; \
    gload16(_s, SMEM + (bi) * 16384 + ((h) * 1024 + tid) * 8);                  \
    gload16(_s + (size_t)64 * 2048, SMEM + (bi) * 16384 + ((h) * 1024 + 512 + tid) * 8); \
  } while (0)

#define QSTAGE_B(bi, st)                                                        \
  do {                                                                          \
    const bf16_t* _s = gB + (size_t)(bcol + r0) * 2048 + (st) * 64 + l0 * 8;    \
    bf16_t* _d = SMEM + 32768 + (bi) * 12288;                                   \
    gload16(_s, _d + tid * 8);                                                  \
    gload16(_s + (size_t)64 * 2048, _d + (512 + tid) * 8);                      \
    gload16(_s + (size_t)128 * 2048, _d + (1024 + tid) * 8);                    \
  } while (0)

#define QLOADA(dst, bi, mh)                                                     \
  _Pragma("unroll")                                                             \
  for (int mq = 0; mq < 4; ++mq) {                                              \
    const int R = wm * 128 + (mh) * 64 + mq * 16 + c15;                         \
    const bf16_t* _a = SMEM + (bi) * 16384;                                     \
    dst[mq][0] = *(const bf16x8*)(_a + (R * 8 + (g ^ (R & 7))) * 8);            \
    dst[mq][1] = *(const bf16x8*)(_a + (R * 8 + ((4 + g) ^ (R & 7))) * 8);      \
  }

#define QLOADB(bi)                                                              \
  _Pragma("unroll")                                                             \
  for (int nq = 0; nq < 3; ++nq) {                                              \
    const int R = wn * 48 + nq * 16 + c15;                                      \
    const bf16_t* _b = SMEM + 32768 + (bi) * 12288;                             \
    bfr[nq][0] = *(const bf16x8*)(_b + (R * 8 + (g ^ (R & 7))) * 8);            \
    bfr[nq][1] = *(const bf16x8*)(_b + (R * 8 + ((4 + g) ^ (R & 7))) * 8);      \
  }

#define QMFMA(afX, mh)                                                          \
  _Pragma("unroll")                                                             \
  for (int nq = 0; nq < 3; ++nq)                                                \
    _Pragma("unroll")                                                           \
    for (int mq = 0; mq < 4; ++mq)                                              \
      acc[(mh) * 4 + mq][nq] =                                                  \
          mfma16(afX[mq][1], bfr[nq][1],                                        \
                 mfma16(afX[mq][0], bfr[nq][0], acc[(mh) * 4 + mq][nq]));

__global__ __launch_bounds__(512, 2) void k_gemm_qkv(
    const bf16_t* __restrict__ gA, const bf16_t* __restrict__ gB,
    const float2* __restrict__ tbl,
    bf16_t* __restrict__ Qp, bf16_t* __restrict__ Kp, bf16_t* __restrict__ Vt) {
  // A: 2 x 256x64 bf16 (64 KB), B: 2 x 192x64 bf16 (48 KB) = 112 KB total.
  // Epilogue reuses the same 112 KB as a 128x193 f32 exchange (98.8 KB).
  __shared__ __align__(16) bf16_t SMEM[2 * 16384 + 2 * 12288];
  const int tid = threadIdx.x;
  const int lane = tid & 63, w = tid >> 6;
  const int c15 = lane & 15, g = lane >> 4;
  const int wm = w >> 2, wn = w & 3;

  const int cpx = (int)gridDim.x >> 3;           // 256 % 8 == 0: bijective
  const int u = ((int)blockIdx.x & 7) * cpx + ((int)blockIdx.x >> 3);
  const int bx = u & 15, by = u >> 4;
  const int brow = by * 256, bcol = bx * 192;

  const int r0 = tid >> 3, p0 = tid & 7;
  const int l0 = p0 ^ (r0 & 7);

  const f32x4 fzero = {0.f, 0.f, 0.f, 0.f};
  f32x4 acc[8][3];
#pragma unroll
  for (int m = 0; m < 8; ++m)
#pragma unroll
    for (int n = 0; n < 3; ++n) acc[m][n] = fzero;

  const int NT = 2048 >> 6;   // 32 K-tiles

  // prologue: tile0 fully (7 loads) + tile1's A0,B (5); gate retires tile0
  QSTAGE_A(0, 0, 0); QSTAGE_A(0, 0, 1); QSTAGE_B(0, 0);
  QSTAGE_A(1, 1, 0); QSTAGE_B(1, 1);
  asm volatile("s_waitcnt vmcnt(5)" ::: "memory");
  __builtin_amdgcn_s_barrier();

  for (int t = 0; t < NT; ++t) {
    const int bi = t & 1, oi = bi ^ 1;
    const int st1 = (t + 1 < NT) ? t + 1 : NT - 1;
    const int st2 = (t + 2 < NT) ? t + 2 : NT - 1;
    bf16x8 af0[4][2], af1[4][2], bfr[3][2];

    // p0: A-half 0 x all B; stage A1(t+1)->oi (its last read was p1(t-1))
    QLOADA(af0, bi, 0);
    QLOADB(bi);
    QSTAGE_A(oi, st1, 1);
    PH_MID();
    QMFMA(af0, 0);
    PH_END();

    // p1: A-half 1 (B regs held); stage A0,B(t+2)->bi (bi reads done @p0);
    //     gate vmcnt(5): retires t+1's 5+2 older loads, leaves t+2's 5
    QLOADA(af1, bi, 1);
    QSTAGE_A(bi, st2, 0);
    QSTAGE_B(bi, st2);
    asm volatile("s_waitcnt vmcnt(5)" ::: "memory");
    PH_MID();
    QMFMA(af1, 1);
    PH_END();
  }

  // ---- epilogue: LDS exchange + RoPE/pack ----
  float* ex = (float*)SMEM;              // 128 x 193 f32 = 98816 B (fits)
  const float QSCALE = 0.125f * 1.44269504088896340736f;
#pragma unroll 1
  for (int eh = 0; eh < 2; ++eh) {
    __syncthreads();                     // LDS free / prev round consumed
    // write: block rows {wm*128 + eh*64 + 0..63} -> lr = wm*64 + (0..63)
#pragma unroll
    for (int mm = 0; mm < 4; ++mm) {
      const int m = eh * 4 + mm;
#pragma unroll
      for (int n = 0; n < 3; ++n)
#pragma unroll
        for (int r = 0; r < 4; ++r) {
          const int lr = wm * 64 + mm * 16 + g * 4 + r;
          ex[lr * 193 + wn * 48 + n * 16 + c15] = acc[m][n][r];
        }
    }
    __syncthreads();
    if (tid < 384) {
      const int lr = tid & 127, hh = tid >> 7;          // 3 head-chunks
      const int grow = brow + (lr >> 6) * 128 + eh * 64 + (lr & 63);
      const int bb = grow >> 11, s = grow & 2047;
      const int gcol = bcol + hh * 64;                  // 64-aligned chunk
      const float* exr = ex + lr * 193 + hh * 64;
      if (gcol < 2048) {                 // ---- Q head: rope + scale ----
        const int hq = gcol >> 6;
        bf16_t o[64];
#pragma unroll
        for (int d2 = 0; d2 < 32; ++d2) {
          const float2 cs = tbl[grow * 32 + d2];
          const float v1 = exr[d2], v2 = exr[32 + d2];
          o[d2]      = (bf16_t)((v1 * cs.x - v2 * cs.y) * QSCALE);
          o[32 + d2] = (bf16_t)((v2 * cs.x + v1 * cs.y) * QSCALE);
        }
        bf16_t* dst = Qp + (((size_t)bb * 32 + hq) * 2048 + s) * 64;
#pragma unroll
        for (int j = 0; j < 8; ++j)
          *(bf16x8*)(dst + j * 8) = *(bf16x8*)(o + j * 8);
      } else {
        const int cc = gcol - 2048;
        const int kvh = cc >> 7;
        if (((cc >> 6) & 1) == 0) {      // ---- K half: rope, unscaled ----
          bf16_t o[64];
#pragma unroll
          for (int d2 = 0; d2 < 32; ++d2) {
            const float2 cs = tbl[grow * 32 + d2];
            const float v1 = exr[d2], v2 = exr[32 + d2];
            o[d2]      = (bf16_t)(v1 * cs.x - v2 * cs.y);
            o[32 + d2] = (bf16_t)(v2 * cs.x + v1 * cs.y);
          }
          bf16_t* dst = Kp + (((size_t)bb * 8 + kvh) * 2048 + s) * 64;
#pragma unroll
          for (int j = 0; j < 8; ++j)
            *(bf16x8*)(dst + j * 8) = *(bf16x8*)(o + j * 8);
        } else {                         // ---- V half -> Vt[d][s] ----
          bf16_t* dst = Vt + (size_t)(bb * 8 + kvh) * 64 * 2048 + s;
#pragma unroll
          for (int d = 0; d < 64; ++d)
            dst[(size_t)d * 2048] = (bf16_t)exr[d];     // coalesced across lanes
        }
      }
    }
  }
}

// =================================================================
// Out-proj GEMM: 256x128 tile (grid 256 = full machine), 8 waves 2x4,
// BK=64, 2 phases/K-tile, counted vmcnt(4). (R10-proven, unchanged.)
// =================================================================
#define OSTAGE_A(bi, st, h)                                                     \
  do {                                                                          \
    const bf16_t* _s = gA + (size_t)(brow + (h) * 128 + r0) * gK + (st) * 64 + l0 * 8; \
    gload16(_s, &As[bi][((h) * 1024 + tid) * 8]);                               \
    gload16(_s + (size_t)64 * gK, &As[bi][((h) * 1024 + 512 + tid) * 8]);       \
  } while (0)

#define OSTAGE_B(bi, st)                                                        \
  do {                                                                          \
    const bf16_t* _s = gB + (size_t)(bcol + r0) * gK + (st) * 64 + l0 * 8;      \
    gload16(_s, &Bs[bi][tid * 8]);                                              \
    gload16(_s + (size_t)64 * gK, &Bs[bi][(512 + tid) * 8]);                    \
  } while (0)

#define OLOADA(dst, bi, mh)                                                     \
  _Pragma("unroll")                                                             \
  for (int mq = 0; mq < 4; ++mq) {                                              \
    const int R = wm * 128 + (mh) * 64 + mq * 16 + c15;                         \
    dst[mq][0] = *(const bf16x8*)(&As[bi][(R * 8 + (g ^ (R & 7))) * 8]);        \
    dst[mq][1] = *(const bf16x8*)(&As[bi][(R * 8 + ((4 + g) ^ (R & 7))) * 8]);  \
  }

#define OLOADB(bi)                                                              \
  _Pragma("unroll")                                                             \
  for (int nq = 0; nq < 2; ++nq) {                                              \
    const int R = wn * 32 + nq * 16 + c15;                                      \
    bfr[nq][0] = *(const bf16x8*)(&Bs[bi][(R * 8 + (g ^ (R & 7))) * 8]);        \
    bfr[nq][1] = *(const bf16x8*)(&Bs[bi][(R * 8 + ((4 + g) ^ (R & 7))) * 8]);  \
  }

#define OMFMAQ(afX, mh)                                                         \
  _Pragma("unroll")                                                             \
  for (int nq = 0; nq < 2; ++nq)                                                \
    _Pragma("unroll")                                                           \
    for (int mq = 0; mq < 4; ++mq)                                              \
      acc[(mh) * 4 + mq][nq] =                                                  \
          mfma16(afX[mq][1], bfr[nq][1],                                        \
                 mfma16(afX[mq][0], bfr[nq][0], acc[(mh) * 4 + mq][nq]));

__global__ __launch_bounds__(512, 2) void k_gemm_out(
    const bf16_t* __restrict__ gA, const bf16_t* __restrict__ gB,
    float* __restrict__ C) {
  __shared__ __align__(16) bf16_t As[2][256 * 64];
  __shared__ __align__(16) bf16_t Bs[2][128 * 64];
  const int gK = 2048, NBX = 16, ldc = 2048;
  const int tid = threadIdx.x;
  const int lane = tid & 63, w = tid >> 6;
  const int c15 = lane & 15, g = lane >> 4;
  const int wm = w >> 2, wn = w & 3;

  const int cpx = (int)gridDim.x >> 3;
  const int u = ((int)blockIdx.x & 7) * cpx + ((int)blockIdx.x >> 3);
  const int bx = u % NBX, by = u / NBX;
  const int brow = by * 256, bcol = bx * 128;

  const int r0 = tid >> 3, p0 = tid & 7;
  const int l0 = p0 ^ (r0 & 7);

  const f32x4 fzero = {0.f, 0.f, 0.f, 0.f};
  f32x4 acc[8][2];
#pragma unroll
  for (int m = 0; m < 8; ++m)
#pragma unroll
    for (int n = 0; n < 2; ++n) acc[m][n] = fzero;

  const int NT = gK >> 6;

  OSTAGE_A(0, 0, 0); OSTAGE_A(0, 0, 1); OSTAGE_B(0, 0);
  OSTAGE_A(1, 1, 0); OSTAGE_B(1, 1);
  asm volatile("s_waitcnt vmcnt(4)" ::: "memory");
  __builtin_amdgcn_s_barrier();

  for (int t = 0; t < NT; ++t) {
    const int bi = t & 1, oi = bi ^ 1;
    const int st1 = (t + 1 < NT) ? t + 1 : NT - 1;
    const int st2 = (t + 2 < NT) ? t + 2 : NT - 1;
    bf16x8 af0[4][2], af1[4][2], bfr[2][2];

    OLOADA(af0, bi, 0);
    OLOADB(bi);
    OSTAGE_A(oi, st1, 1);
    PH_MID();
    OMFMAQ(af0, 0);
    PH_END();

    OLOADA(af1, bi, 1);
    OSTAGE_A(bi, st2, 0);
    OSTAGE_B(bi, st2);
    asm volatile("s_waitcnt vmcnt(4)" ::: "memory");
    PH_MID();
    OMFMAQ(af1, 1);
    PH_END();
  }

#pragma unroll
  for (int m = 0; m < 8; ++m)
#pragma unroll
    for (int n = 0; n < 2; ++n)
#pragma unroll
      for (int r = 0; r < 4; ++r) {
        const int row = brow + wm * 128 + m * 16 + g * 4 + r;
        const int col = bcol + wn * 32 + n * 16 + c15;
        C[(size_t)row * ldc + col] = acc[m][n][r];
      }
}

// ---------------- causal GQA flash attention (R7-proven, unchanged) ----------------
__global__ __launch_bounds__(256, 3) void k_attn(const bf16_t* __restrict__ Qp,
                                                 const bf16_t* __restrict__ Kp,
                                                 const bf16_t* __restrict__ Vt,
                                                 bf16_t* __restrict__ ctx) {
  const int wgid = blockIdx.x;
  const int gidx = wgid & 15;             // (b,kvh) group -> fixed XCD residue
  const int j    = wgid >> 4;
  const int b = gidx >> 3, kvh = gidx & 7;
  const int qs = 63 - j;                  // LPT: heavy q-tiles dispatch first
  const int tid = threadIdx.x, lane = tid & 63, w = tid >> 6;
  const int h = kvh * 4 + w;              // wave = head within the kvh group
  const int c15 = lane & 15, g = lane >> 4;

  __shared__ __align__(16) bf16_t Ks[2][64 * 64];
  __shared__ __align__(16) bf16_t Vs[2][64 * 64];
  __shared__ __align__(16) bf16_t Pw[4][32 * 64];
  bf16_t* pw = &Pw[w][0];

  const int q0 = qs * 32;

  bf16x8 aq[2][2];
#pragma unroll
  for (int m = 0; m < 2; ++m) {
    const bf16_t* Qrow = Qp + (((size_t)b * 32 + h) * 2048 + q0 + m * 16 + c15) * 64;
    aq[m][0] = *(const bf16x8*)(Qrow + g * 8);
    aq[m][1] = *(const bf16x8*)(Qrow + 32 + g * 8);
  }
  asm volatile("s_waitcnt vmcnt(0)" ::: "memory");

  const bf16_t* Kb = Kp + ((size_t)b * 8 + kvh) * (size_t)(2048 * 64);
  const bf16_t* Vb = Vt + ((size_t)b * 8 + kvh) * (size_t)(64 * 2048);

  const int c0 = tid,      r0 = c0 >> 3, l0 = (c0 & 7) ^ (r0 & 7);
  const int c1 = tid + 256, r1 = c1 >> 3, l1 = (c1 & 7) ^ (r1 & 7);
  const int dst0 = (w * 64) * 8, dst1 = (w * 64 + 256) * 8;

  const f32x4 fzero = {0.f, 0.f, 0.f, 0.f};
  f32x4 acc[2][4];
  f32x4 lsum[2];
#pragma unroll
  for (int m = 0; m < 2; ++m) {
    lsum[m] = fzero;
#pragma unroll
    for (int n = 0; n < 4; ++n) acc[m][n] = fzero;
  }
  bf16x8 bones;
#pragma unroll
  for (int j2 = 0; j2 < 8; ++j2) bones[j2] = (bf16_t)1.0f;

  const int ntw = qs / 2 + 1;

  gload16(Kb + (size_t)r0 * 64 + l0 * 8, &Ks[0][dst0]);
  gload16(Kb + (size_t)r1 * 64 + l1 * 8, &Ks[0][dst1]);
  gload16(Vb + (size_t)r0 * 2048 + l0 * 8, &Vs[0][dst0]);
  gload16(Vb + (size_t)r1 * 2048 + l1 * 8, &Vs[0][dst1]);

  for (int t = 0; t < ntw; ++t) {
    const int kvbase = t * 64;
    const int tnb = (t + 1 < ntw ? t + 1 : t) * 64;
    const int nb = (t + 1) & 1, cb = t & 1;

    gload16(Kb + (size_t)(tnb + r0) * 64 + l0 * 8, &Ks[nb][dst0]);
    gload16(Kb + (size_t)(tnb + r1) * 64 + l1 * 8, &Ks[nb][dst1]);
    gload16(Vb + (size_t)r0 * 2048 + tnb + l0 * 8, &Vs[nb][dst0]);
    gload16(Vb + (size_t)r1 * 2048 + tnb + l1 * 8, &Vs[nb][dst1]);
    asm volatile("s_waitcnt vmcnt(4)" ::: "memory");
    __builtin_amdgcn_s_barrier();

    const bf16_t* Kc = &Ks[cb][0];
    f32x4 sv[2][4];
    __builtin_amdgcn_s_setprio(1);
#pragma unroll
    for (int n = 0; n < 4; ++n) {
      const int row = n * 16 + c15;
      const bf16x8 bk0 = *(const bf16x8*)(Kc + row * 64 + ((g ^ (row & 7)) << 3));
      const bf16x8 bk1 = *(const bf16x8*)(Kc + row * 64 + (((4 + g) ^ (row & 7)) << 3));
      sv[0][n] = mfma16(aq[0][1], bk1, mfma16(aq[0][0], bk0, fzero));
      sv[1][n] = mfma16(aq[1][1], bk1, mfma16(aq[1][0], bk0, fzero));
    }
    __builtin_amdgcn_s_setprio(0);

    if (kvbase + 63 > q0) {
#pragma unroll
      for (int n = 0; n < 4; ++n)
#pragma unroll
        for (int r = 0; r < 4; ++r) {
          const int col = kvbase + n * 16 + c15;
          if (col > q0 + g * 4 + r)      sv[0][n][r] = -1e30f;
          if (col > q0 + 16 + g * 4 + r) sv[1][n][r] = -1e30f;
        }
    }
#pragma unroll
    for (int n = 0; n < 4; ++n)
#pragma unroll
      for (int r = 0; r < 4; ++r) {
        const int col = n * 16 + c15;
        const int rp0 = g * 4 + r, rp1 = 16 + g * 4 + r;
        pw[rp0 * 64 + ((((col >> 3) ^ (rp0 & 7)) << 3) | (col & 7))] = (bf16_t)exp2f(sv[0][n][r]);
        pw[rp1 * 64 + ((((col >> 3) ^ (rp1 & 7)) << 3) | (col & 7))] = (bf16_t)exp2f(sv[1][n][r]);
      }
    asm volatile("s_waitcnt lgkmcnt(0)" ::: "memory");
    __builtin_amdgcn_sched_barrier(0);

    bf16x8 ap[2][2];
#pragma unroll
    for (int m = 0; m < 2; ++m) {
      const int q = m * 16 + c15;
      ap[m][0] = *(const bf16x8*)(pw + q * 64 + ((g ^ (q & 7)) << 3));
      ap[m][1] = *(const bf16x8*)(pw + q * 64 + (((4 + g) ^ (q & 7)) << 3));
    }
    const bf16_t* Vc = &Vs[cb][0];
    __builtin_amdgcn_s_setprio(1);
#pragma unroll
    for (int m = 0; m < 2; ++m)
      lsum[m] = mfma16(ap[m][1], bones, mfma16(ap[m][0], bones, lsum[m]));
#pragma unroll
    for (int n = 0; n < 4; ++n) {
      const int row = n * 16 + c15;
      const bf16x8 bv0 = *(const bf16x8*)(Vc + row * 64 + ((g ^ (row & 7)) << 3));
      const bf16x8 bv1 = *(const bf16x8*)(Vc + row * 64 + (((4 + g) ^ (row & 7)) << 3));
#pragma unroll
      for (int m = 0; m < 2; ++m)
        acc[m][n] = mfma16(ap[m][1], bv1, mfma16(ap[m][0], bv0, acc[m][n]));
    }
    __builtin_amdgcn_s_setprio(0);
    __builtin_amdgcn_s_barrier();
  }

#pragma unroll
  for (int m = 0; m < 2; ++m) {
    float inv[4];
#pragma unroll
    for (int r = 0; r < 4; ++r) inv[r] = 1.0f / lsum[m][r];
#pragma unroll
    for (int n = 0; n < 4; ++n)
#pragma unroll
      for (int r = 0; r < 4; ++r) {
        const int rowq = q0 + m * 16 + g * 4 + r;
        const int col = h * 64 + n * 16 + c15;
        ctx[((size_t)b * 2048 + rowq) * 2048 + col] = (bf16_t)(acc[m][n][r] * inv[r]);
      }
  }
}

// ------------------------------------------------------------------
extern "C" void kernel_launch(void* const* d_in, const int* in_sizes, int n_in,
                              void* d_out, int out_size, void* d_ws, size_t ws_size,
                              hipStream_t stream) {
  const float* hs  = (const float*)d_in[0];
  const int*   pos = (const int*)d_in[1];
  const float* Wq  = (const float*)d_in[2];
  const float* Wkv = (const float*)d_in[3];
  const float* Wo  = (const float*)d_in[4];
  float* out = (float*)d_out;
  (void)in_sizes; (void)n_in; (void)out_size; (void)ws_size;

  char* p = (char*)d_ws;
  bf16_t* Xbf   = (bf16_t*)p; p += (size_t)4096 * 2048 * 2;
  bf16_t* Wqkvt = (bf16_t*)p; p += (size_t)3072 * 2048 * 2;
  bf16_t* Wot   = (bf16_t*)p; p += (size_t)2048 * 2048 * 2;
  float2* tbl   = (float2*)p; p += (size_t)4096 * 32 * 8;
  bf16_t* Qp    = (bf16_t*)p; p += (size_t)2 * 32 * 2048 * 64 * 2;
  bf16_t* Kp    = (bf16_t*)p; p += (size_t)2 * 8 * 2048 * 64 * 2;
  bf16_t* Vt    = (bf16_t*)p; p += (size_t)2 * 8 * 64 * 2048 * 2;
  bf16_t* ctx   = (bf16_t*)p; p += (size_t)4096 * 2048 * 2;

  k_prep<<<18944, 256, 0, stream>>>(hs, Xbf, Wq, Wkv, Wo, Wqkvt, Wot, pos, tbl);
  // QKV GEMM (M=4096, N=3072, K=2048), 256x192 tiles -> 256 blocks
  k_gemm_qkv<<<256, 512, 0, stream>>>(Xbf, Wqkvt, tbl, Qp, Kp, Vt);
  k_attn<<<1024, 256, 0, stream>>>(Qp, Kp, Vt, ctx);
  // out-proj GEMM (M=4096, N=2048, K=2048), 256x128 tiles, full coverage
  k_gemm_out<<<256, 512, 0, stream>>>(ctx, Wot, out);
}

// Round 13
// 199.852 us; speedup vs baseline: 1.0547x; 1.0547x over previous
//
#include <hip/hip_runtime.h>

typedef __bf16 bf16_t;
typedef __bf16 bf16x8 __attribute__((ext_vector_type(8)));
typedef __bf16 bf16x4 __attribute__((ext_vector_type(4)));
typedef float f32x4 __attribute__((ext_vector_type(4)));

#define DEV static __device__ __forceinline__

DEV void gload16(const void* g, void* lds) {
  __builtin_amdgcn_global_load_lds((__attribute__((address_space(1))) void*)g,
                                   (__attribute__((address_space(3))) void*)lds, 16, 0, 0);
}

DEV f32x4 mfma16(bf16x8 a, bf16x8 b, f32x4 c) {
  return __builtin_amdgcn_mfma_f32_16x16x32_bf16(a, b, c, 0, 0, 0);
}

// ---------------- fused pre-pass: cvt + rope table + 3 weight transposes ----------------
DEV void transpose_blk(const float* __restrict__ in, bf16_t* __restrict__ out,
                       int R, int C, int bx, int by, int tid, float (*tile)[33]) {
  const int tx = tid & 31, ty = tid >> 5;
  const int rb = by * 32, cb = bx * 32;
#pragma unroll
  for (int i = 0; i < 32; i += 8)
    tile[ty + i][tx] = in[(size_t)(rb + ty + i) * C + (cb + tx)];
  __syncthreads();
#pragma unroll
  for (int i = 0; i < 32; i += 8)
    out[(size_t)(cb + ty + i) * R + (rb + tx)] = (bf16_t)tile[tx][ty + i];
}

__global__ __launch_bounds__(256) void k_prep(const float* __restrict__ hs,
                                              bf16_t* __restrict__ Xbf,
                                              const float* __restrict__ Wq,
                                              const float* __restrict__ Wkv,
                                              const float* __restrict__ Wo,
                                              bf16_t* __restrict__ Wqkvt,
                                              bf16_t* __restrict__ Wot,
                                              const int* __restrict__ pos_ids,
                                              float2* __restrict__ tbl) {
  __shared__ float tile[32][33];
  const int bid = blockIdx.x, tid = threadIdx.x;
  if (bid < 8192) {                              // cvt f32->bf16, 4/thread
    const int i = (bid * 256 + tid) * 4;
    float4 v = *(const float4*)(hs + i);
    bf16x4 o;
    o[0] = (bf16_t)v.x; o[1] = (bf16_t)v.y; o[2] = (bf16_t)v.z; o[3] = (bf16_t)v.w;
    *(bf16x4*)(Xbf + i) = o;
  } else if (bid < 8192 + 512) {                 // rope cos/sin table
    const int token = (bid - 8192) * 8 + (tid >> 5);
    const int d2 = tid & 31;
    const float p = (float)pos_ids[token];
    const float freq = exp2f(-(float)d2 / 32.0f * log2f(10000.0f));
    const float a = p * freq;
    tbl[token * 32 + d2] = make_float2(cosf(a), sinf(a));
  } else if (bid < 8192 + 512 + 4096) {          // Wq^T
    const int local = bid - (8192 + 512);
    transpose_blk(Wq, Wqkvt, 2048, 2048, local & 63, local >> 6, tid, tile);
  } else if (bid < 8192 + 512 + 4096 + 2048) {   // Wkv^T
    const int local = bid - (8192 + 512 + 4096);
    transpose_blk(Wkv, Wqkvt + (size_t)2048 * 2048, 2048, 1024,
                  local & 31, local >> 5, tid, tile);
  } else {                                       // Wo^T
    const int local = bid - (8192 + 512 + 4096 + 2048);
    transpose_blk(Wo, Wot, 2048, 2048, local & 63, local >> 6, tid, tile);
  }
}

// =================================================================
// Shared phase helpers (R9/R10-proven)
// =================================================================
#define PH_MID()                                            \
  __builtin_amdgcn_s_barrier();                             \
  asm volatile("s_waitcnt lgkmcnt(0)" ::: "memory");        \
  __builtin_amdgcn_sched_barrier(0);                        \
  __builtin_amdgcn_s_setprio(1)

#define PH_END()                                            \
  __builtin_amdgcn_s_setprio(0);                            \
  __builtin_amdgcn_s_barrier()

// =================================================================
// QKV GEMM: 256x256 tile, 8 waves, BK=64, 4 phases/K-tile, counted vmcnt,
// fused RoPE/pack epilogue. (R9/R10-proven best: 73 us, 708 TF.)
// =================================================================
#define STAGE_A(bi, st, h)                                                      \
  do {                                                                          \
    const bf16_t* _s = gA + (size_t)(brow + (h) * 128 + r0) * gK + (st) * 64 + l0 * 8; \
    gload16(_s, &As[bi][((h) * 1024 + tid) * 8]);                               \
    gload16(_s + (size_t)64 * gK, &As[bi][((h) * 1024 + 512 + tid) * 8]);       \
  } while (0)

#define STAGE_B(bi, st, h)                                                      \
  do {                                                                          \
    const bf16_t* _s = gB + (size_t)(bcol + (h) * 128 + r0) * gK + (st) * 64 + l0 * 8; \
    gload16(_s, &Bs[bi][((h) * 1024 + tid) * 8]);                               \
    gload16(_s + (size_t)64 * gK, &Bs[bi][((h) * 1024 + 512 + tid) * 8]);       \
  } while (0)

#define LOADA(bi, mh)                                                           \
  _Pragma("unroll")                                                             \
  for (int mq = 0; mq < 4; ++mq) {                                              \
    const int R = wm * 128 + (mh) * 64 + mq * 16 + c15;                         \
    af[mq][0] = *(const bf16x8*)(&As[bi][(R * 8 + (g ^ (R & 7))) * 8]);         \
    af[mq][1] = *(const bf16x8*)(&As[bi][(R * 8 + ((4 + g) ^ (R & 7))) * 8]);   \
  }

#define LOADB(bi, nh)                                                           \
  _Pragma("unroll")                                                             \
  for (int nq = 0; nq < 2; ++nq) {                                              \
    const int R = wn * 64 + ((nh) * 2 + nq) * 16 + c15;                         \
    bfr[nq][0] = *(const bf16x8*)(&Bs[bi][(R * 8 + (g ^ (R & 7))) * 8]);        \
    bfr[nq][1] = *(const bf16x8*)(&Bs[bi][(R * 8 + ((4 + g) ^ (R & 7))) * 8]);  \
  }

#define MFMAQ(mh, nh)                                                           \
  _Pragma("unroll")                                                             \
  for (int nq = 0; nq < 2; ++nq)                                                \
    _Pragma("unroll")                                                           \
    for (int mq = 0; mq < 4; ++mq)                                              \
      acc[(mh) * 4 + mq][(nh) * 2 + nq] =                                       \
          mfma16(af[mq][1], bfr[nq][1],                                         \
                 mfma16(af[mq][0], bfr[nq][0], acc[(mh) * 4 + mq][(nh) * 2 + nq]));

__global__ __launch_bounds__(512, 2) void k_gemm_qkv(
    const bf16_t* __restrict__ gA, const bf16_t* __restrict__ gB,
    const float2* __restrict__ tbl,
    bf16_t* __restrict__ Qp, bf16_t* __restrict__ Kp, bf16_t* __restrict__ Vt) {
  __shared__ __align__(16) bf16_t As[2][256 * 64];
  __shared__ __align__(16) bf16_t Bs[2][256 * 64];
  const int gK = 2048, NBX = 12;
  const int tid = threadIdx.x;
  const int lane = tid & 63, w = tid >> 6;
  const int c15 = lane & 15, g = lane >> 4;
  const int wm = w >> 2, wn = w & 3;

  const int cpx = (int)gridDim.x >> 3;
  const int u = ((int)blockIdx.x & 7) * cpx + ((int)blockIdx.x >> 3);
  const int bx = u % NBX, by = u / NBX;
  const int brow = by * 256, bcol = bx * 256;

  const int r0 = tid >> 3, p0 = tid & 7;
  const int l0 = p0 ^ (r0 & 7);

  const f32x4 fzero = {0.f, 0.f, 0.f, 0.f};
  f32x4 acc[8][4];
#pragma unroll
  for (int m = 0; m < 8; ++m)
#pragma unroll
    for (int n = 0; n < 4; ++n) acc[m][n] = fzero;

  const int NT = gK >> 6;

  STAGE_A(0, 0, 0); STAGE_A(0, 0, 1); STAGE_B(0, 0, 0); STAGE_B(0, 0, 1);
  STAGE_A(1, 1, 0);
  asm volatile("s_waitcnt vmcnt(2)" ::: "memory");
  __builtin_amdgcn_s_barrier();

  for (int t = 0; t < NT; ++t) {
    const int bi = t & 1, oi = bi ^ 1;
    const int st1 = (t + 1 < NT) ? t + 1 : NT - 1;
    const int st2 = (t + 2 < NT) ? t + 2 : NT - 1;
    bf16x8 af[4][2], bfr[2][2];

    LOADA(bi, 0);
    LOADB(bi, 0);
    STAGE_A(oi, st1, 1);
    STAGE_B(oi, st1, 0);
    PH_MID();
    MFMAQ(0, 0);
    PH_END();

    LOADB(bi, 1);
    STAGE_B(oi, st1, 1);
    PH_MID();
    MFMAQ(0, 1);
    PH_END();

    LOADA(bi, 1);
    LOADB(bi, 0);
    PH_MID();
    MFMAQ(1, 0);
    PH_END();

    LOADB(bi, 1);
    STAGE_A(bi, st2, 0);
    asm volatile("s_waitcnt vmcnt(2)" ::: "memory");
    PH_MID();
    MFMAQ(1, 1);
    PH_END();
  }

  // ---- fused RoPE/pack epilogue ----
  const int seg = bcol + wn * 64;
  const int wrow = brow + wm * 128;
  const float QSCALE = 0.125f * 1.44269504088896340736f;
  if (seg < 2048) {                      // ---- Q head ----
    const int hq = seg >> 6;
#pragma unroll
    for (int m = 0; m < 8; ++m)
#pragma unroll
      for (int r = 0; r < 4; ++r) {
        const int row = wrow + m * 16 + g * 4 + r;
        const int bb = row >> 11, s = row & 2047;
        const float2 cs0 = tbl[row * 32 + c15];
        const float2 cs1 = tbl[row * 32 + 16 + c15];
        bf16_t* dst = Qp + (((size_t)bb * 32 + hq) * 2048 + s) * 64;
        dst[c15]      = (bf16_t)((acc[m][0][r] * cs0.x - acc[m][2][r] * cs0.y) * QSCALE);
        dst[32 + c15] = (bf16_t)((acc[m][2][r] * cs0.x + acc[m][0][r] * cs0.y) * QSCALE);
        dst[16 + c15] = (bf16_t)((acc[m][1][r] * cs1.x - acc[m][3][r] * cs1.y) * QSCALE);
        dst[48 + c15] = (bf16_t)((acc[m][3][r] * cs1.x + acc[m][1][r] * cs1.y) * QSCALE);
      }
  } else {
    const int cc = seg - 2048;
    const int kvh = cc >> 7;
    if (((cc >> 6) & 1) == 0) {          // ---- K half (RoPE, unscaled) ----
#pragma unroll
      for (int m = 0; m < 8; ++m)
#pragma unroll
        for (int r = 0; r < 4; ++r) {
          const int row = wrow + m * 16 + g * 4 + r;
          const int bb = row >> 11, s = row & 2047;
          const float2 cs0 = tbl[row * 32 + c15];
          const float2 cs1 = tbl[row * 32 + 16 + c15];
          bf16_t* dst = Kp + (((size_t)bb * 8 + kvh) * 2048 + s) * 64;
          dst[c15]      = (bf16_t)(acc[m][0][r] * cs0.x - acc[m][2][r] * cs0.y);
          dst[32 + c15] = (bf16_t)(acc[m][2][r] * cs0.x + acc[m][0][r] * cs0.y);
          dst[16 + c15] = (bf16_t)(acc[m][1][r] * cs1.x - acc[m][3][r] * cs1.y);
          dst[48 + c15] = (bf16_t)(acc[m][3][r] * cs1.x + acc[m][1][r] * cs1.y);
        }
    } else {                             // ---- V half -> Vt[d][s] ----
#pragma unroll
      for (int m = 0; m < 8; ++m) {
        const int row0 = wrow + m * 16 + g * 4;
        const int bb = row0 >> 11, s0 = row0 & 2047;
#pragma unroll
        for (int n = 0; n < 4; ++n) {
          bf16x4 o;
#pragma unroll
          for (int r = 0; r < 4; ++r) o[r] = (bf16_t)acc[m][n][r];
          const int d = n * 16 + c15;
          *(bf16x4*)(Vt + ((size_t)(bb * 8 + kvh) * 64 + d) * 2048 + s0) = o;
        }
      }
    }
  }
}

// =================================================================
// Out-proj GEMM: 256x128 tile (grid 256 = full machine), 8 waves 2x4,
// BK=64, 2 phases/K-tile, counted vmcnt(4). (R10-proven, unchanged.)
// =================================================================
#define OSTAGE_A(bi, st, h)                                                     \
  do {                                                                          \
    const bf16_t* _s = gA + (size_t)(brow + (h) * 128 + r0) * gK + (st) * 64 + l0 * 8; \
    gload16(_s, &As[bi][((h) * 1024 + tid) * 8]);                               \
    gload16(_s + (size_t)64 * gK, &As[bi][((h) * 1024 + 512 + tid) * 8]);       \
  } while (0)

#define OSTAGE_B(bi, st)                                                        \
  do {                                                                          \
    const bf16_t* _s = gB + (size_t)(bcol + r0) * gK + (st) * 64 + l0 * 8;      \
    gload16(_s, &Bs[bi][tid * 8]);                                              \
    gload16(_s + (size_t)64 * gK, &Bs[bi][(512 + tid) * 8]);                    \
  } while (0)

#define OLOADA(dst, bi, mh)                                                     \
  _Pragma("unroll")                                                             \
  for (int mq = 0; mq < 4; ++mq) {                                              \
    const int R = wm * 128 + (mh) * 64 + mq * 16 + c15;                         \
    dst[mq][0] = *(const bf16x8*)(&As[bi][(R * 8 + (g ^ (R & 7))) * 8]);        \
    dst[mq][1] = *(const bf16x8*)(&As[bi][(R * 8 + ((4 + g) ^ (R & 7))) * 8]);  \
  }

#define OLOADB(bi)                                                              \
  _Pragma("unroll")                                                             \
  for (int nq = 0; nq < 2; ++nq) {                                              \
    const int R = wn * 32 + nq * 16 + c15;                                      \
    bfr[nq][0] = *(const bf16x8*)(&Bs[bi][(R * 8 + (g ^ (R & 7))) * 8]);        \
    bfr[nq][1] = *(const bf16x8*)(&Bs[bi][(R * 8 + ((4 + g) ^ (R & 7))) * 8]);  \
  }

#define OMFMAQ(afX, mh)                                                         \
  _Pragma("unroll")                                                             \
  for (int nq = 0; nq < 2; ++nq)                                                \
    _Pragma("unroll")                                                           \
    for (int mq = 0; mq < 4; ++mq)                                              \
      acc[(mh) * 4 + mq][nq] =                                                  \
          mfma16(afX[mq][1], bfr[nq][1],                                        \
                 mfma16(afX[mq][0], bfr[nq][0], acc[(mh) * 4 + mq][nq]));

__global__ __launch_bounds__(512, 2) void k_gemm_out(
    const bf16_t* __restrict__ gA, const bf16_t* __restrict__ gB,
    float* __restrict__ C) {
  __shared__ __align__(16) bf16_t As[2][256 * 64];
  __shared__ __align__(16) bf16_t Bs[2][128 * 64];
  const int gK = 2048, NBX = 16, ldc = 2048;
  const int tid = threadIdx.x;
  const int lane = tid & 63, w = tid >> 6;
  const int c15 = lane & 15, g = lane >> 4;
  const int wm = w >> 2, wn = w & 3;

  const int cpx = (int)gridDim.x >> 3;
  const int u = ((int)blockIdx.x & 7) * cpx + ((int)blockIdx.x >> 3);
  const int bx = u % NBX, by = u / NBX;
  const int brow = by * 256, bcol = bx * 128;

  const int r0 = tid >> 3, p0 = tid & 7;
  const int l0 = p0 ^ (r0 & 7);

  const f32x4 fzero = {0.f, 0.f, 0.f, 0.f};
  f32x4 acc[8][2];
#pragma unroll
  for (int m = 0; m < 8; ++m)
#pragma unroll
    for (int n = 0; n < 2; ++n) acc[m][n] = fzero;

  const int NT = gK >> 6;

  OSTAGE_A(0, 0, 0); OSTAGE_A(0, 0, 1); OSTAGE_B(0, 0);
  OSTAGE_A(1, 1, 0); OSTAGE_B(1, 1);
  asm volatile("s_waitcnt vmcnt(4)" ::: "memory");
  __builtin_amdgcn_s_barrier();

  for (int t = 0; t < NT; ++t) {
    const int bi = t & 1, oi = bi ^ 1;
    const int st1 = (t + 1 < NT) ? t + 1 : NT - 1;
    const int st2 = (t + 2 < NT) ? t + 2 : NT - 1;
    bf16x8 af0[4][2], af1[4][2], bfr[2][2];

    OLOADA(af0, bi, 0);
    OLOADB(bi);
    OSTAGE_A(oi, st1, 1);
    PH_MID();
    OMFMAQ(af0, 0);
    PH_END();

    OLOADA(af1, bi, 1);
    OSTAGE_A(bi, st2, 0);
    OSTAGE_B(bi, st2);
    asm volatile("s_waitcnt vmcnt(4)" ::: "memory");
    PH_MID();
    OMFMAQ(af1, 1);
    PH_END();
  }

#pragma unroll
  for (int m = 0; m < 8; ++m)
#pragma unroll
    for (int n = 0; n < 2; ++n)
#pragma unroll
      for (int r = 0; r < 4; ++r) {
        const int row = brow + wm * 128 + m * 16 + g * 4 + r;
        const int col = bcol + wn * 32 + n * 16 + c15;
        C[(size_t)row * ldc + col] = acc[m][n][r];
      }
}

// ---------------- causal GQA flash attention (R7-proven; bounds 256,4) ----------------
__global__ __launch_bounds__(256, 4) void k_attn(const bf16_t* __restrict__ Qp,
                                                 const bf16_t* __restrict__ Kp,
                                                 const bf16_t* __restrict__ Vt,
                                                 bf16_t* __restrict__ ctx) {
  const int wgid = blockIdx.x;
  const int gidx = wgid & 15;             // (b,kvh) group -> fixed XCD residue
  const int j    = wgid >> 4;
  const int b = gidx >> 3, kvh = gidx & 7;
  const int qs = 63 - j;                  // LPT: heavy q-tiles dispatch first
  const int tid = threadIdx.x, lane = tid & 63, w = tid >> 6;
  const int h = kvh * 4 + w;              // wave = head within the kvh group
  const int c15 = lane & 15, g = lane >> 4;

  __shared__ __align__(16) bf16_t Ks[2][64 * 64];
  __shared__ __align__(16) bf16_t Vs[2][64 * 64];
  __shared__ __align__(16) bf16_t Pw[4][32 * 64];
  bf16_t* pw = &Pw[w][0];

  const int q0 = qs * 32;

  bf16x8 aq[2][2];
#pragma unroll
  for (int m = 0; m < 2; ++m) {
    const bf16_t* Qrow = Qp + (((size_t)b * 32 + h) * 2048 + q0 + m * 16 + c15) * 64;
    aq[m][0] = *(const bf16x8*)(Qrow + g * 8);
    aq[m][1] = *(const bf16x8*)(Qrow + 32 + g * 8);
  }
  asm volatile("s_waitcnt vmcnt(0)" ::: "memory");

  const bf16_t* Kb = Kp + ((size_t)b * 8 + kvh) * (size_t)(2048 * 64);
  const bf16_t* Vb = Vt + ((size_t)b * 8 + kvh) * (size_t)(64 * 2048);

  const int c0 = tid,      r0 = c0 >> 3, l0 = (c0 & 7) ^ (r0 & 7);
  const int c1 = tid + 256, r1 = c1 >> 3, l1 = (c1 & 7) ^ (r1 & 7);
  const int dst0 = (w * 64) * 8, dst1 = (w * 64 + 256) * 8;

  const f32x4 fzero = {0.f, 0.f, 0.f, 0.f};
  f32x4 acc[2][4];
  f32x4 lsum[2];
#pragma unroll
  for (int m = 0; m < 2; ++m) {
    lsum[m] = fzero;
#pragma unroll
    for (int n = 0; n < 4; ++n) acc[m][n] = fzero;
  }
  bf16x8 bones;
#pragma unroll
  for (int j2 = 0; j2 < 8; ++j2) bones[j2] = (bf16_t)1.0f;

  const int ntw = qs / 2 + 1;

  gload16(Kb + (size_t)r0 * 64 + l0 * 8, &Ks[0][dst0]);
  gload16(Kb + (size_t)r1 * 64 + l1 * 8, &Ks[0][dst1]);
  gload16(Vb + (size_t)r0 * 2048 + l0 * 8, &Vs[0][dst0]);
  gload16(Vb + (size_t)r1 * 2048 + l1 * 8, &Vs[0][dst1]);

  for (int t = 0; t < ntw; ++t) {
    const int kvbase = t * 64;
    const int tnb = (t + 1 < ntw ? t + 1 : t) * 64;
    const int nb = (t + 1) & 1, cb = t & 1;

    gload16(Kb + (size_t)(tnb + r0) * 64 + l0 * 8, &Ks[nb][dst0]);
    gload16(Kb + (size_t)(tnb + r1) * 64 + l1 * 8, &Ks[nb][dst1]);
    gload16(Vb + (size_t)r0 * 2048 + tnb + l0 * 8, &Vs[nb][dst0]);
    gload16(Vb + (size_t)r1 * 2048 + tnb + l1 * 8, &Vs[nb][dst1]);
    asm volatile("s_waitcnt vmcnt(4)" ::: "memory");
    __builtin_amdgcn_s_barrier();

    const bf16_t* Kc = &Ks[cb][0];
    f32x4 sv[2][4];
    __builtin_amdgcn_s_setprio(1);
#pragma unroll
    for (int n = 0; n < 4; ++n) {
      const int row = n * 16 + c15;
      const bf16x8 bk0 = *(const bf16x8*)(Kc + row * 64 + ((g ^ (row & 7)) << 3));
      const bf16x8 bk1 = *(const bf16x8*)(Kc + row * 64 + (((4 + g) ^ (row & 7)) << 3));
      sv[0][n] = mfma16(aq[0][1], bk1, mfma16(aq[0][0], bk0, fzero));
      sv[1][n] = mfma16(aq[1][1], bk1, mfma16(aq[1][0], bk0, fzero));
    }
    __builtin_amdgcn_s_setprio(0);

    if (kvbase + 63 > q0) {
#pragma unroll
      for (int n = 0; n < 4; ++n)
#pragma unroll
        for (int r = 0; r < 4; ++r) {
          const int col = kvbase + n * 16 + c15;
          if (col > q0 + g * 4 + r)      sv[0][n][r] = -1e30f;
          if (col > q0 + 16 + g * 4 + r) sv[1][n][r] = -1e30f;
        }
    }
#pragma unroll
    for (int n = 0; n < 4; ++n)
#pragma unroll
      for (int r = 0; r < 4; ++r) {
        const int col = n * 16 + c15;
        const int rp0 = g * 4 + r, rp1 = 16 + g * 4 + r;
        pw[rp0 * 64 + ((((col >> 3) ^ (rp0 & 7)) << 3) | (col & 7))] = (bf16_t)exp2f(sv[0][n][r]);
        pw[rp1 * 64 + ((((col >> 3) ^ (rp1 & 7)) << 3) | (col & 7))] = (bf16_t)exp2f(sv[1][n][r]);
      }
    asm volatile("s_waitcnt lgkmcnt(0)" ::: "memory");
    __builtin_amdgcn_sched_barrier(0);

    bf16x8 ap[2][2];
#pragma unroll
    for (int m = 0; m < 2; ++m) {
      const int q = m * 16 + c15;
      ap[m][0] = *(const bf16x8*)(pw + q * 64 + ((g ^ (q & 7)) << 3));
      ap[m][1] = *(const bf16x8*)(pw + q * 64 + (((4 + g) ^ (q & 7)) << 3));
    }
    const bf16_t* Vc = &Vs[cb][0];
    __builtin_amdgcn_s_setprio(1);
#pragma unroll
    for (int m = 0; m < 2; ++m)
      lsum[m] = mfma16(ap[m][1], bones, mfma16(ap[m][0], bones, lsum[m]));
#pragma unroll
    for (int n = 0; n < 4; ++n) {
      const int row = n * 16 + c15;
      const bf16x8 bv0 = *(const bf16x8*)(Vc + row * 64 + ((g ^ (row & 7)) << 3));
      const bf16x8 bv1 = *(const bf16x8*)(Vc + row * 64 + (((4 + g) ^ (row & 7)) << 3));
#pragma unroll
      for (int m = 0; m < 2; ++m)
        acc[m][n] = mfma16(ap[m][1], bv1, mfma16(ap[m][0], bv0, acc[m][n]));
    }
    __builtin_amdgcn_s_setprio(0);
    __builtin_amdgcn_s_barrier();
  }

#pragma unroll
  for (int m = 0; m < 2; ++m) {
    float inv[4];
#pragma unroll
    for (int r = 0; r < 4; ++r) inv[r] = 1.0f / lsum[m][r];
#pragma unroll
    for (int n = 0; n < 4; ++n)
#pragma unroll
      for (int r = 0; r < 4; ++r) {
        const int rowq = q0 + m * 16 + g * 4 + r;
        const int col = h * 64 + n * 16 + c15;
        ctx[((size_t)b * 2048 + rowq) * 2048 + col] = (bf16_t)(acc[m][n][r] * inv[r]);
      }
  }
}

// ------------------------------------------------------------------
extern "C" void kernel_launch(void* const* d_in, const int* in_sizes, int n_in,
                              void* d_out, int out_size, void* d_ws, size_t ws_size,
                              hipStream_t stream) {
  const float* hs  = (const float*)d_in[0];
  const int*   pos = (const int*)d_in[1];
  const float* Wq  = (const float*)d_in[2];
  const float* Wkv = (const float*)d_in[3];
  const float* Wo  = (const float*)d_in[4];
  float* out = (float*)d_out;
  (void)in_sizes; (void)n_in; (void)out_size; (void)ws_size;

  char* p = (char*)d_ws;
  bf16_t* Xbf   = (bf16_t*)p; p += (size_t)4096 * 2048 * 2;
  bf16_t* Wqkvt = (bf16_t*)p; p += (size_t)3072 * 2048 * 2;
  bf16_t* Wot   = (bf16_t*)p; p += (size_t)2048 * 2048 * 2;
  float2* tbl   = (float2*)p; p += (size_t)4096 * 32 * 8;
  bf16_t* Qp    = (bf16_t*)p; p += (size_t)2 * 32 * 2048 * 64 * 2;
  bf16_t* Kp    = (bf16_t*)p; p += (size_t)2 * 8 * 2048 * 64 * 2;
  bf16_t* Vt    = (bf16_t*)p; p += (size_t)2 * 8 * 64 * 2048 * 2;
  bf16_t* ctx   = (bf16_t*)p; p += (size_t)4096 * 2048 * 2;

  k_prep<<<18944, 256, 0, stream>>>(hs, Xbf, Wq, Wkv, Wo, Wqkvt, Wot, pos, tbl);
  k_gemm_qkv<<<192, 512, 0, stream>>>(Xbf, Wqkvt, tbl, Qp, Kp, Vt);
  k_attn<<<1024, 256, 0, stream>>>(Qp, Kp, Vt, ctx);
  k_gemm_out<<<256, 512, 0, stream>>>(ctx, Wot, out);
}

// Round 14
// 188.543 us; speedup vs baseline: 1.1180x; 1.0600x over previous
//
#include <hip/hip_runtime.h>

typedef __bf16 bf16_t;
typedef __bf16 bf16x8 __attribute__((ext_vector_type(8)));
typedef __bf16 bf16x4 __attribute__((ext_vector_type(4)));
typedef float f32x4 __attribute__((ext_vector_type(4)));

#define DEV static __device__ __forceinline__

DEV void gload16(const void* g, void* lds) {
  __builtin_amdgcn_global_load_lds((__attribute__((address_space(1))) void*)g,
                                   (__attribute__((address_space(3))) void*)lds, 16, 0, 0);
}

DEV f32x4 mfma16(bf16x8 a, bf16x8 b, f32x4 c) {
  return __builtin_amdgcn_mfma_f32_16x16x32_bf16(a, b, c, 0, 0, 0);
}

// ---------------- fused pre-pass: cvt + rope table + 3 weight transposes ----------------
DEV void transpose_blk(const float* __restrict__ in, bf16_t* __restrict__ out,
                       int R, int C, int bx, int by, int tid, float (*tile)[33]) {
  const int tx = tid & 31, ty = tid >> 5;
  const int rb = by * 32, cb = bx * 32;
#pragma unroll
  for (int i = 0; i < 32; i += 8)
    tile[ty + i][tx] = in[(size_t)(rb + ty + i) * C + (cb + tx)];
  __syncthreads();
#pragma unroll
  for (int i = 0; i < 32; i += 8)
    out[(size_t)(cb + ty + i) * R + (rb + tx)] = (bf16_t)tile[tx][ty + i];
}

__global__ __launch_bounds__(256) void k_prep(const float* __restrict__ hs,
                                              bf16_t* __restrict__ Xbf,
                                              const float* __restrict__ Wq,
                                              const float* __restrict__ Wkv,
                                              const float* __restrict__ Wo,
                                              bf16_t* __restrict__ Wqkvt,
                                              bf16_t* __restrict__ Wot,
                                              const int* __restrict__ pos_ids,
                                              float2* __restrict__ tbl) {
  __shared__ float tile[32][33];
  const int bid = blockIdx.x, tid = threadIdx.x;
  if (bid < 8192) {                              // cvt f32->bf16, 4/thread
    const int i = (bid * 256 + tid) * 4;
    float4 v = *(const float4*)(hs + i);
    bf16x4 o;
    o[0] = (bf16_t)v.x; o[1] = (bf16_t)v.y; o[2] = (bf16_t)v.z; o[3] = (bf16_t)v.w;
    *(bf16x4*)(Xbf + i) = o;
  } else if (bid < 8192 + 512) {                 // rope cos/sin table
    const int token = (bid - 8192) * 8 + (tid >> 5);
    const int d2 = tid & 31;
    const float p = (float)pos_ids[token];
    const float freq = exp2f(-(float)d2 / 32.0f * log2f(10000.0f));
    const float a = p * freq;
    tbl[token * 32 + d2] = make_float2(cosf(a), sinf(a));
  } else if (bid < 8192 + 512 + 4096) {          // Wq^T
    const int local = bid - (8192 + 512);
    transpose_blk(Wq, Wqkvt, 2048, 2048, local & 63, local >> 6, tid, tile);
  } else if (bid < 8192 + 512 + 4096 + 2048) {   // Wkv^T
    const int local = bid - (8192 + 512 + 4096);
    transpose_blk(Wkv, Wqkvt + (size_t)2048 * 2048, 2048, 1024,
                  local & 31, local >> 5, tid, tile);
  } else {                                       // Wo^T
    const int local = bid - (8192 + 512 + 4096 + 2048);
    transpose_blk(Wo, Wot, 2048, 2048, local & 63, local >> 6, tid, tile);
  }
}

// =================================================================
// Shared phase helpers (R9/R10-proven)
// =================================================================
#define PH_MID()                                            \
  __builtin_amdgcn_s_barrier();                             \
  asm volatile("s_waitcnt lgkmcnt(0)" ::: "memory");        \
  __builtin_amdgcn_sched_barrier(0);                        \
  __builtin_amdgcn_s_setprio(1)

#define PH_END()                                            \
  __builtin_amdgcn_s_setprio(0);                            \
  __builtin_amdgcn_s_barrier()

// =================================================================
// QKV GEMM: 256x256 tile, 8 waves, BK=64, 4 phases/K-tile, counted vmcnt,
// fused RoPE/pack epilogue. (R9/R10-proven best: 73 us, 708 TF.)
// =================================================================
#define STAGE_A(bi, st, h)                                                      \
  do {                                                                          \
    const bf16_t* _s = gA + (size_t)(brow + (h) * 128 + r0) * gK + (st) * 64 + l0 * 8; \
    gload16(_s, &As[bi][((h) * 1024 + tid) * 8]);                               \
    gload16(_s + (size_t)64 * gK, &As[bi][((h) * 1024 + 512 + tid) * 8]);       \
  } while (0)

#define STAGE_B(bi, st, h)                                                      \
  do {                                                                          \
    const bf16_t* _s = gB + (size_t)(bcol + (h) * 128 + r0) * gK + (st) * 64 + l0 * 8; \
    gload16(_s, &Bs[bi][((h) * 1024 + tid) * 8]);                               \
    gload16(_s + (size_t)64 * gK, &Bs[bi][((h) * 1024 + 512 + tid) * 8]);       \
  } while (0)

#define LOADA(bi, mh)                                                           \
  _Pragma("unroll")                                                             \
  for (int mq = 0; mq < 4; ++mq) {                                              \
    const int R = wm * 128 + (mh) * 64 + mq * 16 + c15;                         \
    af[mq][0] = *(const bf16x8*)(&As[bi][(R * 8 + (g ^ (R & 7))) * 8]);         \
    af[mq][1] = *(const bf16x8*)(&As[bi][(R * 8 + ((4 + g) ^ (R & 7))) * 8]);   \
  }

#define LOADB(bi, nh)                                                           \
  _Pragma("unroll")                                                             \
  for (int nq = 0; nq < 2; ++nq) {                                              \
    const int R = wn * 64 + ((nh) * 2 + nq) * 16 + c15;                         \
    bfr[nq][0] = *(const bf16x8*)(&Bs[bi][(R * 8 + (g ^ (R & 7))) * 8]);        \
    bfr[nq][1] = *(const bf16x8*)(&Bs[bi][(R * 8 + ((4 + g) ^ (R & 7))) * 8]);  \
  }

#define MFMAQ(mh, nh)                                                           \
  _Pragma("unroll")                                                             \
  for (int nq = 0; nq < 2; ++nq)                                                \
    _Pragma("unroll")                                                           \
    for (int mq = 0; mq < 4; ++mq)                                              \
      acc[(mh) * 4 + mq][(nh) * 2 + nq] =                                       \
          mfma16(af[mq][1], bfr[nq][1],                                         \
                 mfma16(af[mq][0], bfr[nq][0], acc[(mh) * 4 + mq][(nh) * 2 + nq]));

__global__ __launch_bounds__(512, 2) void k_gemm_qkv(
    const bf16_t* __restrict__ gA, const bf16_t* __restrict__ gB,
    const float2* __restrict__ tbl,
    bf16_t* __restrict__ Qp, bf16_t* __restrict__ Kp, bf16_t* __restrict__ Vt) {
  __shared__ __align__(16) bf16_t As[2][256 * 64];
  __shared__ __align__(16) bf16_t Bs[2][256 * 64];
  const int gK = 2048, NBX = 12;
  const int tid = threadIdx.x;
  const int lane = tid & 63, w = tid >> 6;
  const int c15 = lane & 15, g = lane >> 4;
  const int wm = w >> 2, wn = w & 3;

  const int cpx = (int)gridDim.x >> 3;
  const int u = ((int)blockIdx.x & 7) * cpx + ((int)blockIdx.x >> 3);
  const int bx = u % NBX, by = u / NBX;
  const int brow = by * 256, bcol = bx * 256;

  const int r0 = tid >> 3, p0 = tid & 7;
  const int l0 = p0 ^ (r0 & 7);

  const f32x4 fzero = {0.f, 0.f, 0.f, 0.f};
  f32x4 acc[8][4];
#pragma unroll
  for (int m = 0; m < 8; ++m)
#pragma unroll
    for (int n = 0; n < 4; ++n) acc[m][n] = fzero;

  const int NT = gK >> 6;

  STAGE_A(0, 0, 0); STAGE_A(0, 0, 1); STAGE_B(0, 0, 0); STAGE_B(0, 0, 1);
  STAGE_A(1, 1, 0);
  asm volatile("s_waitcnt vmcnt(2)" ::: "memory");
  __builtin_amdgcn_s_barrier();

  for (int t = 0; t < NT; ++t) {
    const int bi = t & 1, oi = bi ^ 1;
    const int st1 = (t + 1 < NT) ? t + 1 : NT - 1;
    const int st2 = (t + 2 < NT) ? t + 2 : NT - 1;
    bf16x8 af[4][2], bfr[2][2];

    LOADA(bi, 0);
    LOADB(bi, 0);
    STAGE_A(oi, st1, 1);
    STAGE_B(oi, st1, 0);
    PH_MID();
    MFMAQ(0, 0);
    PH_END();

    LOADB(bi, 1);
    STAGE_B(oi, st1, 1);
    PH_MID();
    MFMAQ(0, 1);
    PH_END();

    LOADA(bi, 1);
    LOADB(bi, 0);
    PH_MID();
    MFMAQ(1, 0);
    PH_END();

    LOADB(bi, 1);
    STAGE_A(bi, st2, 0);
    asm volatile("s_waitcnt vmcnt(2)" ::: "memory");
    PH_MID();
    MFMAQ(1, 1);
    PH_END();
  }

  // ---- fused RoPE/pack epilogue ----
  const int seg = bcol + wn * 64;
  const int wrow = brow + wm * 128;
  const float QSCALE = 0.125f * 1.44269504088896340736f;
  if (seg < 2048) {                      // ---- Q head ----
    const int hq = seg >> 6;
#pragma unroll
    for (int m = 0; m < 8; ++m)
#pragma unroll
      for (int r = 0; r < 4; ++r) {
        const int row = wrow + m * 16 + g * 4 + r;
        const int bb = row >> 11, s = row & 2047;
        const float2 cs0 = tbl[row * 32 + c15];
        const float2 cs1 = tbl[row * 32 + 16 + c15];
        bf16_t* dst = Qp + (((size_t)bb * 32 + hq) * 2048 + s) * 64;
        dst[c15]      = (bf16_t)((acc[m][0][r] * cs0.x - acc[m][2][r] * cs0.y) * QSCALE);
        dst[32 + c15] = (bf16_t)((acc[m][2][r] * cs0.x + acc[m][0][r] * cs0.y) * QSCALE);
        dst[16 + c15] = (bf16_t)((acc[m][1][r] * cs1.x - acc[m][3][r] * cs1.y) * QSCALE);
        dst[48 + c15] = (bf16_t)((acc[m][3][r] * cs1.x + acc[m][1][r] * cs1.y) * QSCALE);
      }
  } else {
    const int cc = seg - 2048;
    const int kvh = cc >> 7;
    if (((cc >> 6) & 1) == 0) {          // ---- K half (RoPE, unscaled) ----
#pragma unroll
      for (int m = 0; m < 8; ++m)
#pragma unroll
        for (int r = 0; r < 4; ++r) {
          const int row = wrow + m * 16 + g * 4 + r;
          const int bb = row >> 11, s = row & 2047;
          const float2 cs0 = tbl[row * 32 + c15];
          const float2 cs1 = tbl[row * 32 + 16 + c15];
          bf16_t* dst = Kp + (((size_t)bb * 8 + kvh) * 2048 + s) * 64;
          dst[c15]      = (bf16_t)(acc[m][0][r] * cs0.x - acc[m][2][r] * cs0.y);
          dst[32 + c15] = (bf16_t)(acc[m][2][r] * cs0.x + acc[m][0][r] * cs0.y);
          dst[16 + c15] = (bf16_t)(acc[m][1][r] * cs1.x - acc[m][3][r] * cs1.y);
          dst[48 + c15] = (bf16_t)(acc[m][3][r] * cs1.x + acc[m][1][r] * cs1.y);
        }
    } else {                             // ---- V half -> Vt[d][s] ----
#pragma unroll
      for (int m = 0; m < 8; ++m) {
        const int row0 = wrow + m * 16 + g * 4;
        const int bb = row0 >> 11, s0 = row0 & 2047;
#pragma unroll
        for (int n = 0; n < 4; ++n) {
          bf16x4 o;
#pragma unroll
          for (int r = 0; r < 4; ++r) o[r] = (bf16_t)acc[m][n][r];
          const int d = n * 16 + c15;
          *(bf16x4*)(Vt + ((size_t)(bb * 8 + kvh) * 64 + d) * 2048 + s0) = o;
        }
      }
    }
  }
}

// =================================================================
// Out-proj GEMM: 256x128 tile (grid 256 = full machine), 8 waves 2x4,
// BK=64, 2 phases/K-tile, counted vmcnt(4). (R10-proven, unchanged.)
// =================================================================
#define OSTAGE_A(bi, st, h)                                                     \
  do {                                                                          \
    const bf16_t* _s = gA + (size_t)(brow + (h) * 128 + r0) * gK + (st) * 64 + l0 * 8; \
    gload16(_s, &As[bi][((h) * 1024 + tid) * 8]);                               \
    gload16(_s + (size_t)64 * gK, &As[bi][((h) * 1024 + 512 + tid) * 8]);       \
  } while (0)

#define OSTAGE_B(bi, st)                                                        \
  do {                                                                          \
    const bf16_t* _s = gB + (size_t)(bcol + r0) * gK + (st) * 64 + l0 * 8;      \
    gload16(_s, &Bs[bi][tid * 8]);                                              \
    gload16(_s + (size_t)64 * gK, &Bs[bi][(512 + tid) * 8]);                    \
  } while (0)

#define OLOADA(dst, bi, mh)                                                     \
  _Pragma("unroll")                                                             \
  for (int mq = 0; mq < 4; ++mq) {                                              \
    const int R = wm * 128 + (mh) * 64 + mq * 16 + c15;                         \
    dst[mq][0] = *(const bf16x8*)(&As[bi][(R * 8 + (g ^ (R & 7))) * 8]);        \
    dst[mq][1] = *(const bf16x8*)(&As[bi][(R * 8 + ((4 + g) ^ (R & 7))) * 8]);  \
  }

#define OLOADB(bi)                                                              \
  _Pragma("unroll")                                                             \
  for (int nq = 0; nq < 2; ++nq) {                                              \
    const int R = wn * 32 + nq * 16 + c15;                                      \
    bfr[nq][0] = *(const bf16x8*)(&Bs[bi][(R * 8 + (g ^ (R & 7))) * 8]);        \
    bfr[nq][1] = *(const bf16x8*)(&Bs[bi][(R * 8 + ((4 + g) ^ (R & 7))) * 8]);  \
  }

#define OMFMAQ(afX, mh)                                                         \
  _Pragma("unroll")                                                             \
  for (int nq = 0; nq < 2; ++nq)                                                \
    _Pragma("unroll")                                                           \
    for (int mq = 0; mq < 4; ++mq)                                              \
      acc[(mh) * 4 + mq][nq] =                                                  \
          mfma16(afX[mq][1], bfr[nq][1],                                        \
                 mfma16(afX[mq][0], bfr[nq][0], acc[(mh) * 4 + mq][nq]));

__global__ __launch_bounds__(512, 2) void k_gemm_out(
    const bf16_t* __restrict__ gA, const bf16_t* __restrict__ gB,
    float* __restrict__ C) {
  __shared__ __align__(16) bf16_t As[2][256 * 64];
  __shared__ __align__(16) bf16_t Bs[2][128 * 64];
  const int gK = 2048, NBX = 16, ldc = 2048;
  const int tid = threadIdx.x;
  const int lane = tid & 63, w = tid >> 6;
  const int c15 = lane & 15, g = lane >> 4;
  const int wm = w >> 2, wn = w & 3;

  const int cpx = (int)gridDim.x >> 3;
  const int u = ((int)blockIdx.x & 7) * cpx + ((int)blockIdx.x >> 3);
  const int bx = u % NBX, by = u / NBX;
  const int brow = by * 256, bcol = bx * 128;

  const int r0 = tid >> 3, p0 = tid & 7;
  const int l0 = p0 ^ (r0 & 7);

  const f32x4 fzero = {0.f, 0.f, 0.f, 0.f};
  f32x4 acc[8][2];
#pragma unroll
  for (int m = 0; m < 8; ++m)
#pragma unroll
    for (int n = 0; n < 2; ++n) acc[m][n] = fzero;

  const int NT = gK >> 6;

  OSTAGE_A(0, 0, 0); OSTAGE_A(0, 0, 1); OSTAGE_B(0, 0);
  OSTAGE_A(1, 1, 0); OSTAGE_B(1, 1);
  asm volatile("s_waitcnt vmcnt(4)" ::: "memory");
  __builtin_amdgcn_s_barrier();

  for (int t = 0; t < NT; ++t) {
    const int bi = t & 1, oi = bi ^ 1;
    const int st1 = (t + 1 < NT) ? t + 1 : NT - 1;
    const int st2 = (t + 2 < NT) ? t + 2 : NT - 1;
    bf16x8 af0[4][2], af1[4][2], bfr[2][2];

    OLOADA(af0, bi, 0);
    OLOADB(bi);
    OSTAGE_A(oi, st1, 1);
    PH_MID();
    OMFMAQ(af0, 0);
    PH_END();

    OLOADA(af1, bi, 1);
    OSTAGE_A(bi, st2, 0);
    OSTAGE_B(bi, st2);
    asm volatile("s_waitcnt vmcnt(4)" ::: "memory");
    PH_MID();
    OMFMAQ(af1, 1);
    PH_END();
  }

#pragma unroll
  for (int m = 0; m < 8; ++m)
#pragma unroll
    for (int n = 0; n < 2; ++n)
#pragma unroll
      for (int r = 0; r < 4; ++r) {
        const int row = brow + wm * 128 + m * 16 + g * 4 + r;
        const int col = bcol + wn * 32 + n * 16 + c15;
        C[(size_t)row * ldc + col] = acc[m][n][r];
      }
}

// ---------------- causal GQA flash attention (R7-proven; bounds 256,3) ----------------
__global__ __launch_bounds__(256, 3) void k_attn(const bf16_t* __restrict__ Qp,
                                                 const bf16_t* __restrict__ Kp,
                                                 const bf16_t* __restrict__ Vt,
                                                 bf16_t* __restrict__ ctx) {
  const int wgid = blockIdx.x;
  const int gidx = wgid & 15;             // (b,kvh) group -> fixed XCD residue
  const int j    = wgid >> 4;
  const int b = gidx >> 3, kvh = gidx & 7;
  const int qs = 63 - j;                  // LPT: heavy q-tiles dispatch first
  const int tid = threadIdx.x, lane = tid & 63, w = tid >> 6;
  const int h = kvh * 4 + w;              // wave = head within the kvh group
  const int c15 = lane & 15, g = lane >> 4;

  __shared__ __align__(16) bf16_t Ks[2][64 * 64];
  __shared__ __align__(16) bf16_t Vs[2][64 * 64];
  __shared__ __align__(16) bf16_t Pw[4][32 * 64];
  bf16_t* pw = &Pw[w][0];

  const int q0 = qs * 32;

  bf16x8 aq[2][2];
#pragma unroll
  for (int m = 0; m < 2; ++m) {
    const bf16_t* Qrow = Qp + (((size_t)b * 32 + h) * 2048 + q0 + m * 16 + c15) * 64;
    aq[m][0] = *(const bf16x8*)(Qrow + g * 8);
    aq[m][1] = *(const bf16x8*)(Qrow + 32 + g * 8);
  }
  asm volatile("s_waitcnt vmcnt(0)" ::: "memory");

  const bf16_t* Kb = Kp + ((size_t)b * 8 + kvh) * (size_t)(2048 * 64);
  const bf16_t* Vb = Vt + ((size_t)b * 8 + kvh) * (size_t)(64 * 2048);

  const int c0 = tid,      r0 = c0 >> 3, l0 = (c0 & 7) ^ (r0 & 7);
  const int c1 = tid + 256, r1 = c1 >> 3, l1 = (c1 & 7) ^ (r1 & 7);
  const int dst0 = (w * 64) * 8, dst1 = (w * 64 + 256) * 8;

  const f32x4 fzero = {0.f, 0.f, 0.f, 0.f};
  f32x4 acc[2][4];
  f32x4 lsum[2];
#pragma unroll
  for (int m = 0; m < 2; ++m) {
    lsum[m] = fzero;
#pragma unroll
    for (int n = 0; n < 4; ++n) acc[m][n] = fzero;
  }
  bf16x8 bones;
#pragma unroll
  for (int j2 = 0; j2 < 8; ++j2) bones[j2] = (bf16_t)1.0f;

  const int ntw = qs / 2 + 1;

  gload16(Kb + (size_t)r0 * 64 + l0 * 8, &Ks[0][dst0]);
  gload16(Kb + (size_t)r1 * 64 + l1 * 8, &Ks[0][dst1]);
  gload16(Vb + (size_t)r0 * 2048 + l0 * 8, &Vs[0][dst0]);
  gload16(Vb + (size_t)r1 * 2048 + l1 * 8, &Vs[0][dst1]);

  for (int t = 0; t < ntw; ++t) {
    const int kvbase = t * 64;
    const int tnb = (t + 1 < ntw ? t + 1 : t) * 64;
    const int nb = (t + 1) & 1, cb = t & 1;

    gload16(Kb + (size_t)(tnb + r0) * 64 + l0 * 8, &Ks[nb][dst0]);
    gload16(Kb + (size_t)(tnb + r1) * 64 + l1 * 8, &Ks[nb][dst1]);
    gload16(Vb + (size_t)r0 * 2048 + tnb + l0 * 8, &Vs[nb][dst0]);
    gload16(Vb + (size_t)r1 * 2048 + tnb + l1 * 8, &Vs[nb][dst1]);
    asm volatile("s_waitcnt vmcnt(4)" ::: "memory");
    __builtin_amdgcn_s_barrier();

    const bf16_t* Kc = &Ks[cb][0];
    f32x4 sv[2][4];
    __builtin_amdgcn_s_setprio(1);
#pragma unroll
    for (int n = 0; n < 4; ++n) {
      const int row = n * 16 + c15;
      const bf16x8 bk0 = *(const bf16x8*)(Kc + row * 64 + ((g ^ (row & 7)) << 3));
      const bf16x8 bk1 = *(const bf16x8*)(Kc + row * 64 + (((4 + g) ^ (row & 7)) << 3));
      sv[0][n] = mfma16(aq[0][1], bk1, mfma16(aq[0][0], bk0, fzero));
      sv[1][n] = mfma16(aq[1][1], bk1, mfma16(aq[1][0], bk0, fzero));
    }
    __builtin_amdgcn_s_setprio(0);

    if (kvbase + 63 > q0) {
#pragma unroll
      for (int n = 0; n < 4; ++n)
#pragma unroll
        for (int r = 0; r < 4; ++r) {
          const int col = kvbase + n * 16 + c15;
          if (col > q0 + g * 4 + r)      sv[0][n][r] = -1e30f;
          if (col > q0 + 16 + g * 4 + r) sv[1][n][r] = -1e30f;
        }
    }
#pragma unroll
    for (int n = 0; n < 4; ++n)
#pragma unroll
      for (int r = 0; r < 4; ++r) {
        const int col = n * 16 + c15;
        const int rp0 = g * 4 + r, rp1 = 16 + g * 4 + r;
        pw[rp0 * 64 + ((((col >> 3) ^ (rp0 & 7)) << 3) | (col & 7))] = (bf16_t)exp2f(sv[0][n][r]);
        pw[rp1 * 64 + ((((col >> 3) ^ (rp1 & 7)) << 3) | (col & 7))] = (bf16_t)exp2f(sv[1][n][r]);
      }
    asm volatile("s_waitcnt lgkmcnt(0)" ::: "memory");
    __builtin_amdgcn_sched_barrier(0);

    bf16x8 ap[2][2];
#pragma unroll
    for (int m = 0; m < 2; ++m) {
      const int q = m * 16 + c15;
      ap[m][0] = *(const bf16x8*)(pw + q * 64 + ((g ^ (q & 7)) << 3));
      ap[m][1] = *(const bf16x8*)(pw + q * 64 + (((4 + g) ^ (q & 7)) << 3));
    }
    const bf16_t* Vc = &Vs[cb][0];
    __builtin_amdgcn_s_setprio(1);
#pragma unroll
    for (int m = 0; m < 2; ++m)
      lsum[m] = mfma16(ap[m][1], bones, mfma16(ap[m][0], bones, lsum[m]));
#pragma unroll
    for (int n = 0; n < 4; ++n) {
      const int row = n * 16 + c15;
      const bf16x8 bv0 = *(const bf16x8*)(Vc + row * 64 + ((g ^ (row & 7)) << 3));
      const bf16x8 bv1 = *(const bf16x8*)(Vc + row * 64 + (((4 + g) ^ (row & 7)) << 3));
#pragma unroll
      for (int m = 0; m < 2; ++m)
        acc[m][n] = mfma16(ap[m][1], bv1, mfma16(ap[m][0], bv0, acc[m][n]));
    }
    __builtin_amdgcn_s_setprio(0);
    __builtin_amdgcn_s_barrier();
  }

#pragma unroll
  for (int m = 0; m < 2; ++m) {
    float inv[4];
#pragma unroll
    for (int r = 0; r < 4; ++r) inv[r] = 1.0f / lsum[m][r];
#pragma unroll
    for (int n = 0; n < 4; ++n)
#pragma unroll
      for (int r = 0; r < 4; ++r) {
        const int rowq = q0 + m * 16 + g * 4 + r;
        const int col = h * 64 + n * 16 + c15;
        ctx[((size_t)b * 2048 + rowq) * 2048 + col] = (bf16_t)(acc[m][n][r] * inv[r]);
      }
  }
}

// ------------------------------------------------------------------
extern "C" void kernel_launch(void* const* d_in, const int* in_sizes, int n_in,
                              void* d_out, int out_size, void* d_ws, size_t ws_size,
                              hipStream_t stream) {
  const float* hs  = (const float*)d_in[0];
  const int*   pos = (const int*)d_in[1];
  const float* Wq  = (const float*)d_in[2];
  const float* Wkv = (const float*)d_in[3];
  const float* Wo  = (const float*)d_in[4];
  float* out = (float*)d_out;
  (void)in_sizes; (void)n_in; (void)out_size; (void)ws_size;

  char* p = (char*)d_ws;
  bf16_t* Xbf   = (bf16_t*)p; p += (size_t)4096 * 2048 * 2;
  bf16_t* Wqkvt = (bf16_t*)p; p += (size_t)3072 * 2048 * 2;
  bf16_t* Wot   = (bf16_t*)p; p += (size_t)2048 * 2048 * 2;
  float2* tbl   = (float2*)p; p += (size_t)4096 * 32 * 8;
  bf16_t* Qp    = (bf16_t*)p; p += (size_t)2 * 32 * 2048 * 64 * 2;
  bf16_t* Kp    = (bf16_t*)p; p += (size_t)2 * 8 * 2048 * 64 * 2;
  bf16_t* Vt    = (bf16_t*)p; p += (size_t)2 * 8 * 64 * 2048 * 2;
  bf16_t* ctx   = (bf16_t*)p; p += (size_t)4096 * 2048 * 2;

  k_prep<<<18944, 256, 0, stream>>>(hs, Xbf, Wq, Wkv, Wo, Wqkvt, Wot, pos, tbl);
  k_gemm_qkv<<<192, 512, 0, stream>>>(Xbf, Wqkvt, tbl, Qp, Kp, Vt);
  k_attn<<<1024, 256, 0, stream>>>(Qp, Kp, Vt, ctx);
  k_gemm_out<<<256, 512, 0, stream>>>(ctx, Wot, out);
}